// Round 11
// baseline (1303.325 us; speedup 1.0000x reference)
//
#include <hip/hip_runtime.h>

#define H       64
#define NSLOT   4
#define NSTEP   23          // SEQ_LEN - 1
#define NB      65536
#define NV      66          // VOCAB_SIZE + 2
#define SEQL    24
#define LPE     8           // lanes per element
#define TPB     1024        // 16 waves -> 4 waves/SIMD
#define EPB     256         // elements per block (G=2 per lane)
#define ACTSTR  68          // act row stride: conflict-free b128 broadcast reads
#define MROW    68          // sM row stride
#define MSSTR   (64 * MROW + 4)   // slot stride ≡ 4 (mod 32)

// ---- workspace layout (float offsets) ----
#define OFF_EW1   0                  // embW1b  [NV][H] = embed@W1[:64] + b1
#define OFF_EWR1  (NV * H)           // embWr1b [NV][H] = embed@Wr1[:64] + br1
#define OFF_M     (2 * NV * H)       // M [4][64][64] = Ww @ W1slot_s
#define OFF_PB    (OFF_M + NSLOT * H * H)   // pb [4][64] = bw @ W1slot_s
#define OFF_HL    (OFF_PB + NSLOT * H)      // hlast [NB][4][64]  (64 MB)

__global__ __launch_bounds__(256) void k_setup_tables(
    const float* __restrict__ embed, const float* __restrict__ W1, const float* __restrict__ b1,
    const float* __restrict__ Wr1, const float* __restrict__ br1, float* __restrict__ ws)
{
    int idx = blockIdx.x * 256 + threadIdx.x;
    if (idx >= NV * H) return;
    int t = idx >> 6, k = idx & 63;
    float a1 = b1[k], a2 = br1[k];
    for (int j = 0; j < H; ++j) {
        float e = embed[t * H + j];
        a1 = fmaf(e, W1[j * H + k], a1);
        a2 = fmaf(e, Wr1[j * H + k], a2);
    }
    ws[OFF_EW1 + idx]  = a1;
    ws[OFF_EWR1 + idx] = a2;
}

__global__ __launch_bounds__(256) void k_setup_fuse(
    const float* __restrict__ W1, const float* __restrict__ Ww, const float* __restrict__ bw,
    float* __restrict__ ws)
{
    int idx = blockIdx.x * 256 + threadIdx.x;
    if (idx < NSLOT * H * H) {
        int s = idx >> 12, j = (idx >> 6) & 63, k = idx & 63;
        const float* w1s = W1 + (size_t)(H + s * H) * H;   // [p][k]
        float acc = 0.f;
        for (int p = 0; p < H; ++p)
            acc = fmaf(Ww[j * H + p], w1s[p * H + k], acc);
        ws[OFF_M + idx] = acc;
    } else if (idx < NSLOT * H * H + NSLOT * H) {
        int r = idx - NSLOT * H * H;
        int s = r >> 6, k = r & 63;
        const float* w1s = W1 + (size_t)(H + s * H) * H;
        float acc = 0.f;
        for (int p = 0; p < H; ++p)
            acc = fmaf(bw[p], w1s[p * H + k], acc);
        ws[OFF_PB + r] = acc;
    }
}

#define FMA8V(w0, w1, a, ACC) do {                                          \
    ACC[0]=fmaf((a),w0.x,ACC[0]); ACC[1]=fmaf((a),w0.y,ACC[1]);            \
    ACC[2]=fmaf((a),w0.z,ACC[2]); ACC[3]=fmaf((a),w0.w,ACC[3]);            \
    ACC[4]=fmaf((a),w1.x,ACC[4]); ACC[5]=fmaf((a),w1.y,ACC[5]);            \
    ACC[6]=fmaf((a),w1.z,ACC[6]); ACC[7]=fmaf((a),w1.w,ACC[7]);            \
} while (0)

#define LOAD8(ptr, A) do {                                                  \
    const float4* _b = (const float4*)(ptr);                                \
    float4 _b0 = _b[0], _b1 = _b[1];                                        \
    A[0]=_b0.x; A[1]=_b0.y; A[2]=_b0.z; A[3]=_b0.w;                        \
    A[4]=_b1.x; A[5]=_b1.y; A[6]=_b1.z; A[7]=_b1.w;                        \
} while (0)

#define STORE8(rowptr, A) do {                                              \
    float4* _d = (float4*)(rowptr);                                         \
    _d[0] = make_float4(A[0], A[1], A[2], A[3]);                            \
    _d[1] = make_float4(A[4], A[5], A[6], A[7]);                            \
} while (0)

__global__ __launch_bounds__(TPB, 1) void k_main(
    const float* __restrict__ W2, const float* __restrict__ b2,
    const float* __restrict__ Ww, const float* __restrict__ bw,
    const float* __restrict__ We, const float* __restrict__ be,
    const float* __restrict__ Wr1, const float* __restrict__ Wr2, const float* __restrict__ br2,
    const int* __restrict__ qtok, const int* __restrict__ seqs,
    const float* __restrict__ ws, float* hl, float* __restrict__ out)
{
    __shared__ float sM[NSLOT * MSSTR];    // fused Ww@W1slot matrices (lgkm pipe) ~70 KB
    __shared__ float sAct[EPB * ACTSTR];   // [elem][j] rows, b128 broadcast reads ~70 KB
    __shared__ float sPb[NSLOT * 68];      // pb_s rows
    __shared__ float sWeS[8 * 36];         // per-chunk We slices [m][i*4+s]

    const int tid  = threadIdx.x;
    const int m    = tid & (LPE - 1);
    const int g    = tid >> 3;             // element group 0..127 (8 lanes, same wave)
    const int eA   = g;
    const int eB   = g + 128;
    const int gidA = blockIdx.x * EPB + eA;
    const int gidB = blockIdx.x * EPB + eB;
    const int k0   = m * 8;

    // ---- stage LDS ----
    if (tid < 256) {                        // sM: 256 rows x 64 floats
        int s = tid >> 6, j = tid & 63;
        const float4* src = (const float4*)(ws + OFF_M + (size_t)(s * H + j) * H);
        float4* dst = (float4*)(sM + s * MSSTR + j * MROW);
#pragma unroll
        for (int k = 0; k < 16; ++k) dst[k] = src[k];
    }
    if (tid >= 256 && tid < 512) {
        int r = tid - 256;                  // sPb: 4 x 64
        int s = r >> 6, k = r & 63;
        sPb[s * 68 + k] = ws[OFF_PB + s * H + k];
    }
    if (tid >= 512 && tid < 768) {
        int r = tid - 512;                  // sWeS[m][i*4+s] = We[(m*8+i)*4+s]
        int mm = r >> 5, rem = r & 31;
        sWeS[mm * 36 + rem] = We[r];
    }
    __syncthreads();

    const float* embW1b  = ws + OFF_EW1;
    const float* embWr1b = ws + OFF_EWR1;
    float* hlA = hl + (size_t)gidA * (NSLOT * H) + k0;
    float* hlB = hl + (size_t)gidB * (NSLOT * H) + k0;

    // register state per element: pmem 4x8 + contrib 8 + written-mask
    float pA0[8], pA1[8], pA2[8], pA3[8], cA[8];
    float pB0[8], pB1[8], pB2[8], pB3[8], cB[8];
#pragma unroll
    for (int i = 0; i < 8; ++i) {
        pA0[i]=0.f; pA1[i]=0.f; pA2[i]=0.f; pA3[i]=0.f; cA[i]=0.f;
        pB0[i]=0.f; pB1[i]=0.f; pB2[i]=0.f; pB3[i]=0.f; cB[i]=0.f;
    }
    int maskA = 0, maskB = 0;

    float b2r[8];
    LOAD8(b2 + k0, b2r);
    const float4 be4 = *(const float4*)be;

    int tokA = seqs[gidA * SEQL];
    int tokB = seqs[gidB * SEQL];

    float accA[8], accB[8];
    float* rowA = sAct + eA * ACTSTR;
    float* rowB = sAct + eB * ACTSTR;

#pragma unroll 1
    for (int t = 0; t < NSTEP; ++t) {
        int tokAn = seqs[gidA * SEQL + t + 1];
        int tokBn = seqs[gidB * SEQL + t + 1];

        // h1 = relu(embW1b[tok] + contrib) -> act rows
        {
            float hA[8], hB[8];
            LOAD8(embW1b + tokA * H + k0, hA);
            LOAD8(embW1b + tokB * H + k0, hB);
#pragma unroll
            for (int i = 0; i < 8; ++i) {
                hA[i] = fmaxf(hA[i] + cA[i], 0.f);
                hB[i] = fmaxf(hB[i] + cB[i], 0.f);
            }
            STORE8(rowA + k0, hA);
            STORE8(rowB + k0, hB);
        }

        // h2 = relu(h1 @ W2 + b2)   (W2 via VMEM; act b128 LDS broadcast)
#pragma unroll
        for (int i = 0; i < 8; ++i) { accA[i] = b2r[i]; accB[i] = b2r[i]; }
#pragma unroll 4
        for (int jq = 0; jq < 16; ++jq) {
            float4 a4 = *(const float4*)(rowA + jq * 4);
            float4 b4 = *(const float4*)(rowB + jq * 4);
            float aAv[4] = {a4.x, a4.y, a4.z, a4.w};
            float aBv[4] = {b4.x, b4.y, b4.z, b4.w};
#pragma unroll
            for (int jj = 0; jj < 4; ++jj) {
                const float4* w = (const float4*)(W2 + (jq * 4 + jj) * H + k0);
                float4 w0 = w[0], w1 = w[1];
                FMA8V(w0, w1, aAv[jj], accA);
                FMA8V(w0, w1, aBv[jj], accB);
            }
        }
        float h2A[8], h2B[8];
#pragma unroll
        for (int i = 0; i < 8; ++i) {
            h2A[i] = fmaxf(accA[i], 0.f);
            h2B[i] = fmaxf(accB[i], 0.f);
        }
        STORE8(rowA + k0, h2A);
        STORE8(rowB + k0, h2B);

        // evict logits in-register, then 8-lane butterfly sum
        float lA0 = 0.f, lA1 = 0.f, lA2 = 0.f, lA3 = 0.f;
        float lB0 = 0.f, lB1 = 0.f, lB2 = 0.f, lB3 = 0.f;
        {
            const float* wsl = sWeS + m * 36;
#pragma unroll
            for (int i = 0; i < 8; ++i) {
                float4 we4 = *(const float4*)(wsl + i * 4);
                lA0 = fmaf(h2A[i], we4.x, lA0); lA1 = fmaf(h2A[i], we4.y, lA1);
                lA2 = fmaf(h2A[i], we4.z, lA2); lA3 = fmaf(h2A[i], we4.w, lA3);
                lB0 = fmaf(h2B[i], we4.x, lB0); lB1 = fmaf(h2B[i], we4.y, lB1);
                lB2 = fmaf(h2B[i], we4.z, lB2); lB3 = fmaf(h2B[i], we4.w, lB3);
            }
        }
#pragma unroll
        for (int d = 1; d <= 4; d <<= 1) {
            lA0 += __shfl_xor(lA0, d); lA1 += __shfl_xor(lA1, d);
            lA2 += __shfl_xor(lA2, d); lA3 += __shfl_xor(lA3, d);
            lB0 += __shfl_xor(lB0, d); lB1 += __shfl_xor(lB1, d);
            lB2 += __shfl_xor(lB2, d); lB3 += __shfl_xor(lB3, d);
        }
        lA0 += be4.x; lA1 += be4.y; lA2 += be4.z; lA3 += be4.w;
        lB0 += be4.x; lB1 += be4.y; lB2 += be4.z; lB3 += be4.w;

        int eSA = 0; float bstA = lA0;               // first-max wins = jnp.argmax
        if (lA1 > bstA) { bstA = lA1; eSA = 1; }
        if (lA2 > bstA) { bstA = lA2; eSA = 2; }
        if (lA3 > bstA) { bstA = lA3; eSA = 3; }
        int eSB = 0; float bstB = lB0;
        if (lB1 > bstB) { bstB = lB1; eSB = 1; }
        if (lB2 > bstB) { bstB = lB2; eSB = 2; }
        if (lB3 > bstB) { bstB = lB3; eSB = 3; }

        bool a0 = (eSA == 0), a1 = (eSA == 1), a2 = (eSA == 2), a3 = (eSA == 3);
        bool b0 = (eSB == 0), b1 = (eSB == 1), b2_ = (eSB == 2), b3 = (eSB == 3);

        // hlast[e] <- h2  (global, fire-and-forget; read back only at tail)
        STORE8(hlA + eSA * H, h2A);
        STORE8(hlB + eSB * H, h2B);
        maskA |= (1 << eSA);
        maskB |= (1 << eSB);

        // pv = h2 @ M_e + pb_e   (M via LDS; act rows hold h2)
        LOAD8(sPb + eSA * 68 + k0, accA);
        LOAD8(sPb + eSB * 68 + k0, accB);
        const float* lMA = sM + eSA * MSSTR + k0;
        const float* lMB = sM + eSB * MSSTR + k0;
#pragma unroll 4
        for (int jq = 0; jq < 16; ++jq) {
            float4 a4 = *(const float4*)(rowA + jq * 4);
            float4 b4 = *(const float4*)(rowB + jq * 4);
            float dAv[4] = {a4.x, a4.y, a4.z, a4.w};
            float dBv[4] = {b4.x, b4.y, b4.z, b4.w};
#pragma unroll
            for (int jj = 0; jj < 4; ++jj) {
                int j = jq * 4 + jj;
                const float4* wa = (const float4*)(lMA + j * MROW);
                const float4* wb = (const float4*)(lMB + j * MROW);
                float4 wa0 = wa[0], wa1 = wa[1];
                float4 wb0 = wb[0], wb1 = wb[1];
                FMA8V(wa0, wa1, dAv[jj], accA);
                FMA8V(wb0, wb1, dBv[jj], accB);
            }
        }

        // contrib += pv - pmem[e] ; pmem[e] = pv
#pragma unroll
        for (int i = 0; i < 8; ++i) {
            float pvA = accA[i], pvB = accB[i];
            float oldA = a0 ? pA0[i] : a1 ? pA1[i] : a2 ? pA2[i] : pA3[i];
            float oldB = b0 ? pB0[i] : b1 ? pB1[i] : b2_ ? pB2[i] : pB3[i];
            cA[i] += pvA - oldA;
            cB[i] += pvB - oldB;
            pA0[i] = a0 ? pvA : pA0[i];  pA1[i] = a1 ? pvA : pA1[i];
            pA2[i] = a2 ? pvA : pA2[i];  pA3[i] = a3 ? pvA : pA3[i];
            pB0[i] = b0 ? pvB : pB0[i];  pB1[i] = b1 ? pvB : pB1[i];
            pB2[i] = b2_ ? pvB : pB2[i]; pB3[i] = b3 ? pvB : pB3[i];
        }

        tokA = tokAn; tokB = tokBn;
    }

    // ---- tail: hsum = sum of surviving hlast slots (read back from global) ----
    __threadfence();   // drain hlast stores before read-back
    {
        float hsA[8] = {0,0,0,0,0,0,0,0}, hsB[8] = {0,0,0,0,0,0,0,0};
#pragma unroll
        for (int s = 0; s < NSLOT; ++s) {
            float vA[8], vB[8];
            LOAD8(hlA + s * H, vA);
            LOAD8(hlB + s * H, vB);
            float fA = ((maskA >> s) & 1) ? 1.f : 0.f;
            float fB = ((maskB >> s) & 1) ? 1.f : 0.f;
#pragma unroll
            for (int i = 0; i < 8; ++i) {
                hsA[i] = fmaf(fA, vA[i], hsA[i]);
                hsB[i] = fmaf(fB, vB[i], hsB[i]);
            }
        }
        STORE8(rowA + k0, hsA);
        STORE8(rowB + k0, hsB);
    }

    // msum = (hsum @ Ww + cnt*bw) / 4
    {
        float bwr[8];
        LOAD8(bw + k0, bwr);
        float cntA = (float)__popc(maskA), cntB = (float)__popc(maskB);
#pragma unroll
        for (int i = 0; i < 8; ++i) { accA[i] = cntA * bwr[i]; accB[i] = cntB * bwr[i]; }
    }
#pragma unroll 4
    for (int jq = 0; jq < 16; ++jq) {
        float4 a4 = *(const float4*)(rowA + jq * 4);
        float4 b4 = *(const float4*)(rowB + jq * 4);
        float aAv[4] = {a4.x, a4.y, a4.z, a4.w};
        float aBv[4] = {b4.x, b4.y, b4.z, b4.w};
#pragma unroll
        for (int jj = 0; jj < 4; ++jj) {
            const float4* w = (const float4*)(Ww + (jq * 4 + jj) * H + k0);
            float4 w0 = w[0], w1 = w[1];
            FMA8V(w0, w1, aAv[jj], accA);
            FMA8V(w0, w1, aBv[jj], accB);
        }
    }
    {
        float msA[8], msB[8];
#pragma unroll
        for (int i = 0; i < 8; ++i) {
            msA[i] = accA[i] * 0.25f;
            msB[i] = accB[i] * 0.25f;
        }
        STORE8(rowA + k0, msA);
        STORE8(rowB + k0, msB);
    }

    // r2 = relu(embWr1b[q] + msum @ Wr1[64:128])
    int qA = qtok[gidA], qB = qtok[gidB];
    LOAD8(embWr1b + qA * H + k0, accA);
    LOAD8(embWr1b + qB * H + k0, accB);
#pragma unroll 4
    for (int jq = 0; jq < 16; ++jq) {
        float4 a4 = *(const float4*)(rowA + jq * 4);
        float4 b4 = *(const float4*)(rowB + jq * 4);
        float aAv[4] = {a4.x, a4.y, a4.z, a4.w};
        float aBv[4] = {b4.x, b4.y, b4.z, b4.w};
#pragma unroll
        for (int jj = 0; jj < 4; ++jj) {
            const float4* w = (const float4*)(Wr1 + (H + jq * 4 + jj) * H + k0);
            float4 w0 = w[0], w1 = w[1];
            FMA8V(w0, w1, aAv[jj], accA);
            FMA8V(w0, w1, aBv[jj], accB);
        }
    }
    {
        float rA[8], rB[8];
#pragma unroll
        for (int i = 0; i < 8; ++i) {
            rA[i] = fmaxf(accA[i], 0.f);
            rB[i] = fmaxf(accB[i], 0.f);
        }
        STORE8(rowA + k0, rA);
        STORE8(rowB + k0, rB);
    }

    // logits = r2 @ Wr2 + br2
    LOAD8(br2 + k0, accA);
#pragma unroll
    for (int i = 0; i < 8; ++i) accB[i] = accA[i];
#pragma unroll 4
    for (int jq = 0; jq < 16; ++jq) {
        float4 a4 = *(const float4*)(rowA + jq * 4);
        float4 b4 = *(const float4*)(rowB + jq * 4);
        float aAv[4] = {a4.x, a4.y, a4.z, a4.w};
        float aBv[4] = {b4.x, b4.y, b4.z, b4.w};
#pragma unroll
        for (int jj = 0; jj < 4; ++jj) {
            const float4* w = (const float4*)(Wr2 + (jq * 4 + jj) * H + k0);
            float4 w0 = w[0], w1 = w[1];
            FMA8V(w0, w1, aAv[jj], accA);
            FMA8V(w0, w1, aBv[jj], accB);
        }
    }

    float4* oA = (float4*)(out + (size_t)gidA * H + k0);
    oA[0] = make_float4(accA[0], accA[1], accA[2], accA[3]);
    oA[1] = make_float4(accA[4], accA[5], accA[6], accA[7]);
    float4* oB = (float4*)(out + (size_t)gidB * H + k0);
    oB[0] = make_float4(accB[0], accB[1], accB[2], accB[3]);
    oB[1] = make_float4(accB[4], accB[5], accB[6], accB[7]);
}

extern "C" void kernel_launch(void* const* d_in, const int* in_sizes, int n_in,
                              void* d_out, int out_size, void* d_ws, size_t ws_size,
                              hipStream_t stream)
{
    const int*   seqs  = (const int*)d_in[0];
    const int*   qtok  = (const int*)d_in[1];
    const float* embed = (const float*)d_in[2];
    const float* W1    = (const float*)d_in[3];
    const float* b1    = (const float*)d_in[4];
    const float* W2    = (const float*)d_in[5];
    const float* b2    = (const float*)d_in[6];
    const float* Ww    = (const float*)d_in[7];
    const float* bw    = (const float*)d_in[8];
    const float* We    = (const float*)d_in[9];
    const float* be    = (const float*)d_in[10];
    const float* Wr1   = (const float*)d_in[11];
    const float* br1   = (const float*)d_in[12];
    const float* Wr2   = (const float*)d_in[13];
    const float* br2   = (const float*)d_in[14];
    float* out = (float*)d_out;
    float* ws  = (float*)d_ws;

    hipLaunchKernelGGL(k_setup_tables, dim3((NV * H + 255) / 256), dim3(256), 0, stream,
                       embed, W1, b1, Wr1, br1, ws);
    hipLaunchKernelGGL(k_setup_fuse, dim3((NSLOT * H * H + NSLOT * H + 255) / 256), dim3(256),
                       0, stream, W1, Ww, bw, ws);
    hipLaunchKernelGGL(k_main, dim3(NB / EPB), dim3(TPB), 0, stream,
                       W2, b2, Ww, bw, We, be, Wr1, Wr2, br2, qtok, seqs,
                       ws, ws + OFF_HL, out);
}

// Round 12
// 810.729 us; speedup vs baseline: 1.6076x; 1.6076x over previous
//
#include <hip/hip_runtime.h>

#define H       64
#define NSLOT   4
#define NSTEP   23          // SEQ_LEN - 1
#define NB      65536
#define NV      66          // VOCAB_SIZE + 2
#define SEQL    24
#define LPE     8           // lanes per element
#define TPB     512         // 8 waves (R10-proven: 128-VGPR budget, no spill)
#define EPB     128         // elements per block (G=2 per lane)
#define ACTSTR  68          // act row stride: conflict-free b128 broadcast reads
#define MROW    68          // sM row stride
#define JL      48          // M rows j<JL from LDS; j>=JL from global (pipe balance)
#define MSSTR   (JL * MROW + 4)   // slot stride ≡ 4 (mod 32)

// ---- workspace layout (float offsets) ----
#define OFF_EW1   0                  // embW1b  [NV][H] = embed@W1[:64] + b1
#define OFF_EWR1  (NV * H)           // embWr1b [NV][H] = embed@Wr1[:64] + br1
#define OFF_M     (2 * NV * H)       // M [4][64][64] = Ww @ W1slot_s
#define OFF_PB    (OFF_M + NSLOT * H * H)   // pb [4][64] = bw @ W1slot_s
#define OFF_HL    (OFF_PB + NSLOT * H)      // hlast [NB][4][64]  (64 MB)

__global__ __launch_bounds__(256) void k_setup_tables(
    const float* __restrict__ embed, const float* __restrict__ W1, const float* __restrict__ b1,
    const float* __restrict__ Wr1, const float* __restrict__ br1, float* __restrict__ ws)
{
    int idx = blockIdx.x * 256 + threadIdx.x;
    if (idx >= NV * H) return;
    int t = idx >> 6, k = idx & 63;
    float a1 = b1[k], a2 = br1[k];
    for (int j = 0; j < H; ++j) {
        float e = embed[t * H + j];
        a1 = fmaf(e, W1[j * H + k], a1);
        a2 = fmaf(e, Wr1[j * H + k], a2);
    }
    ws[OFF_EW1 + idx]  = a1;
    ws[OFF_EWR1 + idx] = a2;
}

__global__ __launch_bounds__(256) void k_setup_fuse(
    const float* __restrict__ W1, const float* __restrict__ Ww, const float* __restrict__ bw,
    float* __restrict__ ws)
{
    int idx = blockIdx.x * 256 + threadIdx.x;
    if (idx < NSLOT * H * H) {
        int s = idx >> 12, j = (idx >> 6) & 63, k = idx & 63;
        const float* w1s = W1 + (size_t)(H + s * H) * H;   // [p][k]
        float acc = 0.f;
        for (int p = 0; p < H; ++p)
            acc = fmaf(Ww[j * H + p], w1s[p * H + k], acc);
        ws[OFF_M + idx] = acc;
    } else if (idx < NSLOT * H * H + NSLOT * H) {
        int r = idx - NSLOT * H * H;
        int s = r >> 6, k = r & 63;
        const float* w1s = W1 + (size_t)(H + s * H) * H;
        float acc = 0.f;
        for (int p = 0; p < H; ++p)
            acc = fmaf(bw[p], w1s[p * H + k], acc);
        ws[OFF_PB + r] = acc;
    }
}

#define FMA8V(w0, w1, a, ACC) do {                                          \
    ACC[0]=fmaf((a),w0.x,ACC[0]); ACC[1]=fmaf((a),w0.y,ACC[1]);            \
    ACC[2]=fmaf((a),w0.z,ACC[2]); ACC[3]=fmaf((a),w0.w,ACC[3]);            \
    ACC[4]=fmaf((a),w1.x,ACC[4]); ACC[5]=fmaf((a),w1.y,ACC[5]);            \
    ACC[6]=fmaf((a),w1.z,ACC[6]); ACC[7]=fmaf((a),w1.w,ACC[7]);            \
} while (0)

#define LOAD8(ptr, A) do {                                                  \
    const float4* _b = (const float4*)(ptr);                                \
    float4 _b0 = _b[0], _b1 = _b[1];                                        \
    A[0]=_b0.x; A[1]=_b0.y; A[2]=_b0.z; A[3]=_b0.w;                        \
    A[4]=_b1.x; A[5]=_b1.y; A[6]=_b1.z; A[7]=_b1.w;                        \
} while (0)

#define STORE8(rowptr, A) do {                                              \
    float4* _d = (float4*)(rowptr);                                         \
    _d[0] = make_float4(A[0], A[1], A[2], A[3]);                            \
    _d[1] = make_float4(A[4], A[5], A[6], A[7]);                            \
} while (0)

__global__ __launch_bounds__(TPB, 1) void k_main(
    const float* __restrict__ W2, const float* __restrict__ b2,
    const float* __restrict__ Ww, const float* __restrict__ bw,
    const float* __restrict__ We, const float* __restrict__ be,
    const float* __restrict__ Wr1, const float* __restrict__ Wr2, const float* __restrict__ br2,
    const int* __restrict__ qtok, const int* __restrict__ seqs,
    const float* __restrict__ ws, float* hl, float* __restrict__ out)
{
    __shared__ float sM[NSLOT * MSSTR];    // M rows j<JL (lgkm pipe) ~52 KB
    __shared__ float sAct[EPB * ACTSTR];   // [elem][j] rows, b128 broadcast reads ~35 KB
    __shared__ float sPb[NSLOT * 68];      // pb_s rows
    __shared__ float sWeS[8 * 36];         // per-chunk We slices [m][i*4+s]

    const int tid  = threadIdx.x;
    const int m    = tid & (LPE - 1);
    const int g    = tid >> 3;             // element group 0..63 (8 lanes, same wave)
    const int eA   = g;
    const int eB   = g + 64;
    const int gidA = blockIdx.x * EPB + eA;
    const int gidB = blockIdx.x * EPB + eB;
    const int k0   = m * 8;

    // ---- stage LDS ----
    if (tid < 256) {                        // sM: rows j<JL of each slot
        int s = tid >> 6, j = tid & 63;
        if (j < JL) {
            const float4* src = (const float4*)(ws + OFF_M + (size_t)(s * H + j) * H);
            float4* dst = (float4*)(sM + s * MSSTR + j * MROW);
#pragma unroll
            for (int k = 0; k < 16; ++k) dst[k] = src[k];
        }
    }
    if (tid >= 256 && tid < 512) {
        int r = tid - 256;                  // sPb: 4 x 64
        int s = r >> 6, k = r & 63;
        sPb[s * 68 + k] = ws[OFF_PB + s * H + k];
    }
    if (tid < 256) {
        int mm = tid >> 5, rem = tid & 31;  // sWeS[m][i*4+s] = We[(m*8+i)*4+s]
        sWeS[mm * 36 + rem] = We[tid];
    }
    __syncthreads();

    const float* embW1b  = ws + OFF_EW1;
    const float* embWr1b = ws + OFF_EWR1;
    const float* Mg      = ws + OFF_M;      // global M (rows j>=JL read from here)
    float* hlA = hl + (size_t)gidA * (NSLOT * H) + k0;
    float* hlB = hl + (size_t)gidB * (NSLOT * H) + k0;

    // register state per element: pmem 4x8 + contrib 8 + written-mask
    float pA0[8], pA1[8], pA2[8], pA3[8], cA[8];
    float pB0[8], pB1[8], pB2[8], pB3[8], cB[8];
#pragma unroll
    for (int i = 0; i < 8; ++i) {
        pA0[i]=0.f; pA1[i]=0.f; pA2[i]=0.f; pA3[i]=0.f; cA[i]=0.f;
        pB0[i]=0.f; pB1[i]=0.f; pB2[i]=0.f; pB3[i]=0.f; cB[i]=0.f;
    }
    int maskA = 0, maskB = 0;

    float b2r[8];
    LOAD8(b2 + k0, b2r);
    const float4 be4 = *(const float4*)be;

    int tokA = seqs[gidA * SEQL];
    int tokB = seqs[gidB * SEQL];

    float accA[8], accB[8];
    float* rowA = sAct + eA * ACTSTR;
    float* rowB = sAct + eB * ACTSTR;

#pragma unroll 1
    for (int t = 0; t < NSTEP; ++t) {
        int tokAn = seqs[gidA * SEQL + t + 1];
        int tokBn = seqs[gidB * SEQL + t + 1];

        // h1 = relu(embW1b[tok] + contrib) -> act rows
        {
            float hA[8], hB[8];
            LOAD8(embW1b + tokA * H + k0, hA);
            LOAD8(embW1b + tokB * H + k0, hB);
#pragma unroll
            for (int i = 0; i < 8; ++i) {
                hA[i] = fmaxf(hA[i] + cA[i], 0.f);
                hB[i] = fmaxf(hB[i] + cB[i], 0.f);
            }
            STORE8(rowA + k0, hA);
            STORE8(rowB + k0, hB);
        }

        // h2 = relu(h1 @ W2 + b2)   (W2 via VMEM; act b128 LDS broadcast)
#pragma unroll
        for (int i = 0; i < 8; ++i) { accA[i] = b2r[i]; accB[i] = b2r[i]; }
#pragma unroll 4
        for (int jq = 0; jq < 16; ++jq) {
            float4 a4 = *(const float4*)(rowA + jq * 4);
            float4 b4 = *(const float4*)(rowB + jq * 4);
            float aAv[4] = {a4.x, a4.y, a4.z, a4.w};
            float aBv[4] = {b4.x, b4.y, b4.z, b4.w};
#pragma unroll
            for (int jj = 0; jj < 4; ++jj) {
                const float4* w = (const float4*)(W2 + (jq * 4 + jj) * H + k0);
                float4 w0 = w[0], w1 = w[1];
                FMA8V(w0, w1, aAv[jj], accA);
                FMA8V(w0, w1, aBv[jj], accB);
            }
        }
        float h2A[8], h2B[8];
#pragma unroll
        for (int i = 0; i < 8; ++i) {
            h2A[i] = fmaxf(accA[i], 0.f);
            h2B[i] = fmaxf(accB[i], 0.f);
        }
        STORE8(rowA + k0, h2A);
        STORE8(rowB + k0, h2B);

        // evict logits in-register, then 8-lane butterfly sum
        float lA0 = 0.f, lA1 = 0.f, lA2 = 0.f, lA3 = 0.f;
        float lB0 = 0.f, lB1 = 0.f, lB2 = 0.f, lB3 = 0.f;
        {
            const float* wsl = sWeS + m * 36;
#pragma unroll
            for (int i = 0; i < 8; ++i) {
                float4 we4 = *(const float4*)(wsl + i * 4);
                lA0 = fmaf(h2A[i], we4.x, lA0); lA1 = fmaf(h2A[i], we4.y, lA1);
                lA2 = fmaf(h2A[i], we4.z, lA2); lA3 = fmaf(h2A[i], we4.w, lA3);
                lB0 = fmaf(h2B[i], we4.x, lB0); lB1 = fmaf(h2B[i], we4.y, lB1);
                lB2 = fmaf(h2B[i], we4.z, lB2); lB3 = fmaf(h2B[i], we4.w, lB3);
            }
        }
#pragma unroll
        for (int d = 1; d <= 4; d <<= 1) {
            lA0 += __shfl_xor(lA0, d); lA1 += __shfl_xor(lA1, d);
            lA2 += __shfl_xor(lA2, d); lA3 += __shfl_xor(lA3, d);
            lB0 += __shfl_xor(lB0, d); lB1 += __shfl_xor(lB1, d);
            lB2 += __shfl_xor(lB2, d); lB3 += __shfl_xor(lB3, d);
        }
        lA0 += be4.x; lA1 += be4.y; lA2 += be4.z; lA3 += be4.w;
        lB0 += be4.x; lB1 += be4.y; lB2 += be4.z; lB3 += be4.w;

        int eSA = 0; float bstA = lA0;               // first-max wins = jnp.argmax
        if (lA1 > bstA) { bstA = lA1; eSA = 1; }
        if (lA2 > bstA) { bstA = lA2; eSA = 2; }
        if (lA3 > bstA) { bstA = lA3; eSA = 3; }
        int eSB = 0; float bstB = lB0;
        if (lB1 > bstB) { bstB = lB1; eSB = 1; }
        if (lB2 > bstB) { bstB = lB2; eSB = 2; }
        if (lB3 > bstB) { bstB = lB3; eSB = 3; }

        bool a0 = (eSA == 0), a1 = (eSA == 1), a2 = (eSA == 2), a3 = (eSA == 3);
        bool b0 = (eSB == 0), b1 = (eSB == 1), b2_ = (eSB == 2), b3 = (eSB == 3);

        // hlast[e] <- h2  (global, fire-and-forget; read back only at tail)
        STORE8(hlA + eSA * H, h2A);
        STORE8(hlB + eSB * H, h2B);
        maskA |= (1 << eSA);
        maskB |= (1 << eSB);

        // pv = h2 @ M_e + pb_e   — rows j<JL from LDS, rows j>=JL from global.
        // Split is on the (uniform, compile-time) loop index: no lane divergence.
        LOAD8(sPb + eSA * 68 + k0, accA);
        LOAD8(sPb + eSB * 68 + k0, accB);
        const float* lMA = sM + eSA * MSSTR + k0;
        const float* lMB = sM + eSB * MSSTR + k0;
#pragma unroll 4
        for (int jq = 0; jq < JL / 4; ++jq) {
            float4 a4 = *(const float4*)(rowA + jq * 4);
            float4 b4 = *(const float4*)(rowB + jq * 4);
            float dAv[4] = {a4.x, a4.y, a4.z, a4.w};
            float dBv[4] = {b4.x, b4.y, b4.z, b4.w};
#pragma unroll
            for (int jj = 0; jj < 4; ++jj) {
                int j = jq * 4 + jj;
                const float4* wa = (const float4*)(lMA + j * MROW);
                const float4* wb = (const float4*)(lMB + j * MROW);
                float4 wa0 = wa[0], wa1 = wa[1];
                float4 wb0 = wb[0], wb1 = wb[1];
                FMA8V(wa0, wa1, dAv[jj], accA);
                FMA8V(wb0, wb1, dBv[jj], accB);
            }
        }
        {
            const float* gMA = Mg + (size_t)(eSA * H + JL) * H + k0;  // rows JL..63
            const float* gMB = Mg + (size_t)(eSB * H + JL) * H + k0;
#pragma unroll 2
            for (int jq = JL / 4; jq < 16; ++jq) {
                float4 a4 = *(const float4*)(rowA + jq * 4);
                float4 b4 = *(const float4*)(rowB + jq * 4);
                float dAv[4] = {a4.x, a4.y, a4.z, a4.w};
                float dBv[4] = {b4.x, b4.y, b4.z, b4.w};
#pragma unroll
                for (int jj = 0; jj < 4; ++jj) {
                    int jr = (jq * 4 + jj) - JL;   // row offset within global part
                    const float4* wa = (const float4*)(gMA + jr * H);
                    const float4* wb = (const float4*)(gMB + jr * H);
                    float4 wa0 = wa[0], wa1 = wa[1];
                    float4 wb0 = wb[0], wb1 = wb[1];
                    FMA8V(wa0, wa1, dAv[jj], accA);
                    FMA8V(wb0, wb1, dBv[jj], accB);
                }
            }
        }

        // contrib += pv - pmem[e] ; pmem[e] = pv
#pragma unroll
        for (int i = 0; i < 8; ++i) {
            float pvA = accA[i], pvB = accB[i];
            float oldA = a0 ? pA0[i] : a1 ? pA1[i] : a2 ? pA2[i] : pA3[i];
            float oldB = b0 ? pB0[i] : b1 ? pB1[i] : b2_ ? pB2[i] : pB3[i];
            cA[i] += pvA - oldA;
            cB[i] += pvB - oldB;
            pA0[i] = a0 ? pvA : pA0[i];  pA1[i] = a1 ? pvA : pA1[i];
            pA2[i] = a2 ? pvA : pA2[i];  pA3[i] = a3 ? pvA : pA3[i];
            pB0[i] = b0 ? pvB : pB0[i];  pB1[i] = b1 ? pvB : pB1[i];
            pB2[i] = b2_ ? pvB : pB2[i]; pB3[i] = b3 ? pvB : pB3[i];
        }

        tokA = tokAn; tokB = tokBn;
    }

    // ---- tail: hsum = sum of surviving hlast slots (read back from global) ----
    __threadfence();   // drain hlast stores before read-back
    {
        float hsA[8] = {0,0,0,0,0,0,0,0}, hsB[8] = {0,0,0,0,0,0,0,0};
#pragma unroll
        for (int s = 0; s < NSLOT; ++s) {
            float vA[8], vB[8];
            LOAD8(hlA + s * H, vA);
            LOAD8(hlB + s * H, vB);
            float fA = ((maskA >> s) & 1) ? 1.f : 0.f;
            float fB = ((maskB >> s) & 1) ? 1.f : 0.f;
#pragma unroll
            for (int i = 0; i < 8; ++i) {
                hsA[i] = fmaf(fA, vA[i], hsA[i]);
                hsB[i] = fmaf(fB, vB[i], hsB[i]);
            }
        }
        STORE8(rowA + k0, hsA);
        STORE8(rowB + k0, hsB);
    }

    // msum = (hsum @ Ww + cnt*bw) / 4
    {
        float bwr[8];
        LOAD8(bw + k0, bwr);
        float cntA = (float)__popc(maskA), cntB = (float)__popc(maskB);
#pragma unroll
        for (int i = 0; i < 8; ++i) { accA[i] = cntA * bwr[i]; accB[i] = cntB * bwr[i]; }
    }
#pragma unroll 4
    for (int jq = 0; jq < 16; ++jq) {
        float4 a4 = *(const float4*)(rowA + jq * 4);
        float4 b4 = *(const float4*)(rowB + jq * 4);
        float aAv[4] = {a4.x, a4.y, a4.z, a4.w};
        float aBv[4] = {b4.x, b4.y, b4.z, b4.w};
#pragma unroll
        for (int jj = 0; jj < 4; ++jj) {
            const float4* w = (const float4*)(Ww + (jq * 4 + jj) * H + k0);
            float4 w0 = w[0], w1 = w[1];
            FMA8V(w0, w1, aAv[jj], accA);
            FMA8V(w0, w1, aBv[jj], accB);
        }
    }
    {
        float msA[8], msB[8];
#pragma unroll
        for (int i = 0; i < 8; ++i) {
            msA[i] = accA[i] * 0.25f;
            msB[i] = accB[i] * 0.25f;
        }
        STORE8(rowA + k0, msA);
        STORE8(rowB + k0, msB);
    }

    // r2 = relu(embWr1b[q] + msum @ Wr1[64:128])
    int qA = qtok[gidA], qB = qtok[gidB];
    LOAD8(embWr1b + qA * H + k0, accA);
    LOAD8(embWr1b + qB * H + k0, accB);
#pragma unroll 4
    for (int jq = 0; jq < 16; ++jq) {
        float4 a4 = *(const float4*)(rowA + jq * 4);
        float4 b4 = *(const float4*)(rowB + jq * 4);
        float aAv[4] = {a4.x, a4.y, a4.z, a4.w};
        float aBv[4] = {b4.x, b4.y, b4.z, b4.w};
#pragma unroll
        for (int jj = 0; jj < 4; ++jj) {
            const float4* w = (const float4*)(Wr1 + (H + jq * 4 + jj) * H + k0);
            float4 w0 = w[0], w1 = w[1];
            FMA8V(w0, w1, aAv[jj], accA);
            FMA8V(w0, w1, aBv[jj], accB);
        }
    }
    {
        float rA[8], rB[8];
#pragma unroll
        for (int i = 0; i < 8; ++i) {
            rA[i] = fmaxf(accA[i], 0.f);
            rB[i] = fmaxf(accB[i], 0.f);
        }
        STORE8(rowA + k0, rA);
        STORE8(rowB + k0, rB);
    }

    // logits = r2 @ Wr2 + br2
    LOAD8(br2 + k0, accA);
#pragma unroll
    for (int i = 0; i < 8; ++i) accB[i] = accA[i];
#pragma unroll 4
    for (int jq = 0; jq < 16; ++jq) {
        float4 a4 = *(const float4*)(rowA + jq * 4);
        float4 b4 = *(const float4*)(rowB + jq * 4);
        float aAv[4] = {a4.x, a4.y, a4.z, a4.w};
        float aBv[4] = {b4.x, b4.y, b4.z, b4.w};
#pragma unroll
        for (int jj = 0; jj < 4; ++jj) {
            const float4* w = (const float4*)(Wr2 + (jq * 4 + jj) * H + k0);
            float4 w0 = w[0], w1 = w[1];
            FMA8V(w0, w1, aAv[jj], accA);
            FMA8V(w0, w1, aBv[jj], accB);
        }
    }

    float4* oA = (float4*)(out + (size_t)gidA * H + k0);
    oA[0] = make_float4(accA[0], accA[1], accA[2], accA[3]);
    oA[1] = make_float4(accA[4], accA[5], accA[6], accA[7]);
    float4* oB = (float4*)(out + (size_t)gidB * H + k0);
    oB[0] = make_float4(accB[0], accB[1], accB[2], accB[3]);
    oB[1] = make_float4(accB[4], accB[5], accB[6], accB[7]);
}

extern "C" void kernel_launch(void* const* d_in, const int* in_sizes, int n_in,
                              void* d_out, int out_size, void* d_ws, size_t ws_size,
                              hipStream_t stream)
{
    const int*   seqs  = (const int*)d_in[0];
    const int*   qtok  = (const int*)d_in[1];
    const float* embed = (const float*)d_in[2];
    const float* W1    = (const float*)d_in[3];
    const float* b1    = (const float*)d_in[4];
    const float* W2    = (const float*)d_in[5];
    const float* b2    = (const float*)d_in[6];
    const float* Ww    = (const float*)d_in[7];
    const float* bw    = (const float*)d_in[8];
    const float* We    = (const float*)d_in[9];
    const float* be    = (const float*)d_in[10];
    const float* Wr1   = (const float*)d_in[11];
    const float* br1   = (const float*)d_in[12];
    const float* Wr2   = (const float*)d_in[13];
    const float* br2   = (const float*)d_in[14];
    float* out = (float*)d_out;
    float* ws  = (float*)d_ws;

    hipLaunchKernelGGL(k_setup_tables, dim3((NV * H + 255) / 256), dim3(256), 0, stream,
                       embed, W1, b1, Wr1, br1, ws);
    hipLaunchKernelGGL(k_setup_fuse, dim3((NSLOT * H * H + NSLOT * H + 255) / 256), dim3(256),
                       0, stream, W1, Ww, bw, ws);
    hipLaunchKernelGGL(k_main, dim3(NB / EPB), dim3(TPB), 0, stream,
                       W2, b2, Ww, bw, We, be, Wr1, Wr2, br2, qtok, seqs,
                       ws, ws + OFF_HL, out);
}